// Round 1
// baseline (226.399 us; speedup 1.0000x reference)
//
#include <hip/hip_runtime.h>
#include <cstddef>

typedef float  f32x4  __attribute__((ext_vector_type(4)));
typedef __bf16 bf16x8 __attribute__((ext_vector_type(8)));
typedef __bf16 bf16x4 __attribute__((ext_vector_type(4)));

#define DEV static __device__ __forceinline__

DEV float sigf(float x){ return 1.f/(1.f+__expf(-x)); }
DEV float tanh_f(float x){
  x = fminf(fmaxf(x, -20.f), 20.f);
  float e = __expf(2.f*x);
  return (e-1.f)/(e+1.f);
}

DEV bf16x8 cvt8(const float4 a, const float4 b){
  bf16x8 r;
  r[0]=(__bf16)a.x; r[1]=(__bf16)a.y; r[2]=(__bf16)a.z; r[3]=(__bf16)a.w;
  r[4]=(__bf16)b.x; r[5]=(__bf16)b.y; r[6]=(__bf16)b.z; r[7]=(__bf16)b.w;
  return r;
}

// ---------------- ph = h_last @ W_ph^T : (128,256) ----------------
__global__ void k_ph(const float* __restrict__ h0, const float* __restrict__ W_ph,
                     float* __restrict__ ph)
{
  const int b = blockIdx.x, a = threadIdx.x;
  __shared__ float h_s[1024];
  for (int k = a; k < 1024; k += 256) h_s[k] = h0[(size_t)b*1024 + k];
  __syncthreads();
  const float* wr = W_ph + (size_t)a*1024;
  float acc = 0.f;
  for (int k = 0; k < 1024; k += 4){
    float4 w = *(const float4*)(wr + k);
    acc += w.x*h_s[k] + w.y*h_s[k+1] + w.z*h_s[k+2] + w.w*h_s[k+3];
  }
  ph[b*256 + a] = acc;
}

// ---------------- xh[:,0:512]=embed, xh[:,1024:2048]=h0 ----------------
__global__ void k_concat(const float* __restrict__ embed, const float* __restrict__ h0,
                         float* __restrict__ xh)
{
  const int b = blockIdx.x, tid = threadIdx.x;
  *(float2*)(xh + (size_t)b*2048 + tid*2) = *(const float2*)(embed + (size_t)b*512 + tid*2);
  *(float4*)(xh + (size_t)b*2048 + 1024 + tid*4) = *(const float4*)(h0 + (size_t)b*1024 + tid*4);
}

// ---------------- scores[b,t] = w_fc2 . tanh(ph[b] + enc[b,t]@W_pe^T) ----------------
// block: 128 t-rows x 256 attn cols, 4 waves (each 32 t-rows), bf16 MFMA 16x16x32
__global__ __launch_bounds__(256,2) void k_scores(
    const float* __restrict__ enc, const float* __restrict__ W_pe,
    const float* __restrict__ ph, const float* __restrict__ w_fc2,
    float* __restrict__ scores)
{
  const int b  = blockIdx.y;
  const int t0 = blockIdx.x * 128;
  const int tid = threadIdx.x;
  const int w = tid >> 6, lane = tid & 63;
  const int la = lane & 15, g = lane >> 4;

  __shared__ __align__(16) __bf16 A_s[128][40];   // enc tile, pad 40 (80B rows)
  __shared__ __align__(16) __bf16 B_s[256][40];   // W_pe tile
  __shared__ float ph_s[256];
  __shared__ float w2_s[256];

  ph_s[tid] = ph[b*256 + tid];
  w2_s[tid] = w_fc2[tid];

  f32x4 acc[2][16];
  #pragma unroll
  for (int i = 0; i < 2; ++i)
    #pragma unroll
    for (int j = 0; j < 16; ++j) acc[i][j] = (f32x4){0.f,0.f,0.f,0.f};

  const int ar = tid >> 1;
  const int ac = (tid & 1) * 16;
  const float* aptr = enc + ((size_t)b*512 + (t0 + ar))*512 + ac;
  const float* bptr = W_pe + (size_t)tid*512;

  for (int kk = 0; kk < 512; kk += 32){
    { // stage A: 128 x 32 f32 -> bf16
      const float* p = aptr + kk;
      float4 v0 = *(const float4*)(p);
      float4 v1 = *(const float4*)(p+4);
      float4 v2 = *(const float4*)(p+8);
      float4 v3 = *(const float4*)(p+12);
      *(bf16x8*)&A_s[ar][ac]   = cvt8(v0,v1);
      *(bf16x8*)&A_s[ar][ac+8] = cvt8(v2,v3);
    }
    { // stage B: 256 x 32, thread = one W_pe row
      const float* p = bptr + kk;
      float4 v0 = *(const float4*)(p);
      float4 v1 = *(const float4*)(p+4);
      float4 v2 = *(const float4*)(p+8);
      float4 v3 = *(const float4*)(p+12);
      float4 v4 = *(const float4*)(p+16);
      float4 v5 = *(const float4*)(p+20);
      float4 v6 = *(const float4*)(p+24);
      float4 v7 = *(const float4*)(p+28);
      *(bf16x8*)&B_s[tid][0]  = cvt8(v0,v1);
      *(bf16x8*)&B_s[tid][8]  = cvt8(v2,v3);
      *(bf16x8*)&B_s[tid][16] = cvt8(v4,v5);
      *(bf16x8*)&B_s[tid][24] = cvt8(v6,v7);
    }
    __syncthreads();
    bf16x8 af0 = *(const bf16x8*)&A_s[w*32 + la][g*8];
    bf16x8 af1 = *(const bf16x8*)&A_s[w*32 + 16 + la][g*8];
    #pragma unroll
    for (int nf = 0; nf < 16; ++nf){
      bf16x8 bf = *(const bf16x8*)&B_s[nf*16 + la][g*8];
      acc[0][nf] = __builtin_amdgcn_mfma_f32_16x16x32_bf16(af0, bf, acc[0][nf], 0,0,0);
      acc[1][nf] = __builtin_amdgcn_mfma_f32_16x16x32_bf16(af1, bf, acc[1][nf], 0,0,0);
    }
    __syncthreads();
  }

  // epilogue: s[t] = sum_a tanh(pe + ph[a]) * w2[a]; D: row=(g*4+r), col=la
  #pragma unroll
  for (int mfi = 0; mfi < 2; ++mfi){
    #pragma unroll
    for (int r = 0; r < 4; ++r){
      float s = 0.f;
      #pragma unroll
      for (int nf = 0; nf < 16; ++nf){
        float v = acc[mfi][nf][r] + ph_s[nf*16 + la];
        s += tanh_f(v) * w2_s[nf*16 + la];
      }
      s += __shfl_xor(s, 1, 16);
      s += __shfl_xor(s, 2, 16);
      s += __shfl_xor(s, 4, 16);
      s += __shfl_xor(s, 8, 16);
      if (la == 0){
        int t = t0 + w*32 + mfi*16 + g*4 + r;
        scores[b*512 + t] = s;
      }
    }
  }
}

// ---------------- softmax over T=512 per batch row (in-place ok) ----------------
__global__ void k_softmax(const float* __restrict__ scores, const unsigned char* __restrict__ mask,
                          float* __restrict__ aw)
{
  const int b = blockIdx.x, tid = threadIdx.x;
  float s0 = scores[b*512 + tid];
  float s1 = scores[b*512 + 256 + tid];
  if (mask[b*512 + tid])       s0 = -1e30f;
  if (mask[b*512 + 256 + tid]) s1 = -1e30f;
  float m = fmaxf(s0, s1);
  #pragma unroll
  for (int o = 32; o; o >>= 1) m = fmaxf(m, __shfl_xor(m, o, 64));
  __shared__ float redm[4], reds[4];
  const int wv = tid >> 6, l = tid & 63;
  if (l == 0) redm[wv] = m;
  __syncthreads();
  m = fmaxf(fmaxf(redm[0], redm[1]), fmaxf(redm[2], redm[3]));
  float e0 = __expf(s0 - m), e1 = __expf(s1 - m);
  float ss = e0 + e1;
  #pragma unroll
  for (int o = 32; o; o >>= 1) ss += __shfl_xor(ss, o, 64);
  if (l == 0) reds[wv] = ss;
  __syncthreads();
  ss = reds[0] + reds[1] + reds[2] + reds[3];
  float inv = 1.f / ss;
  aw[b*512 + tid]       = e0 * inv;
  aw[b*512 + 256 + tid] = e1 * inv;
}

// ---------------- ctxt partials: part[q][b][e] = sum_{t in q} aw[b,t]*enc[b,t,e] ----------------
__global__ void k_ctxt(const float* __restrict__ enc, const float* __restrict__ aw,
                       float* __restrict__ part)
{
  const int b = blockIdx.x, q = blockIdx.y, tid = threadIdx.x;
  const float* ep = enc + ((size_t)b*512 + q*128)*512;
  const float* ap = aw + b*512 + q*128;
  float ax = 0.f, ay = 0.f;
  for (int t = 0; t < 128; ++t){
    float wgt = ap[t];
    float2 e = *(const float2*)(ep + (size_t)t*512 + tid*2);
    ax += wgt * e.x;
    ay += wgt * e.y;
  }
  float2 r; r.x = ax; r.y = ay;
  *(float2*)(part + ((size_t)q*128 + b)*512 + tid*2) = r;
}

// ---------------- finalize ctxt -> xh[:,512:1024], hc[:,1024:1536] ----------------
__global__ void k_ctxt_fin(const float* __restrict__ part, float* __restrict__ xh,
                           float* __restrict__ hc)
{
  const int b = blockIdx.x, tid = threadIdx.x;
  const int e = tid*2;
  float sx = 0.f, sy = 0.f;
  #pragma unroll
  for (int q = 0; q < 4; ++q){
    float2 p = *(const float2*)(part + ((size_t)q*128 + b)*512 + e);
    sx += p.x; sy += p.y;
  }
  float2 r; r.x = sx; r.y = sy;
  *(float2*)(xh + (size_t)b*2048 + 512 + e) = r;
  *(float2*)(hc + (size_t)b*1536 + 1024 + e) = r;
}

// ---------------- generic C[128,N] = act(A[128,K] @ [W1|W2]^T + b1 + b2) ----------------
// A contiguous (lda). W row j: k<ksplit -> W1[j,k], else W2[j,k-ksplit].
__global__ __launch_bounds__(256,2) void k_gemm(
    const float* __restrict__ A, int lda,
    const float* __restrict__ W1, int ldw1,
    const float* __restrict__ W2, int ldw2, int ksplit,
    const float* __restrict__ bias1, const float* __restrict__ bias2,
    float* __restrict__ C, int ldc, int K, int act)
{
  const int jt = blockIdx.x * 32;
  const int tid = threadIdx.x;
  const int w = tid >> 6, lane = tid & 63;
  const int la = lane & 15, g = lane >> 4;

  __shared__ __align__(16) __bf16 A_s[128][40];
  __shared__ __align__(16) __bf16 B_s[32][40];

  f32x4 acc[2][2];
  #pragma unroll
  for (int i = 0; i < 2; ++i)
    #pragma unroll
    for (int j = 0; j < 2; ++j) acc[i][j] = (f32x4){0.f,0.f,0.f,0.f};

  const int ar = tid >> 1, ac = (tid & 1) * 16;
  const int br = tid >> 3, bc = (tid & 7) * 4;

  for (int kk = 0; kk < K; kk += 32){
    { // stage A 128x32
      const float* p = A + (size_t)ar*lda + kk + ac;
      float4 v0 = *(const float4*)(p);
      float4 v1 = *(const float4*)(p+4);
      float4 v2 = *(const float4*)(p+8);
      float4 v3 = *(const float4*)(p+12);
      *(bf16x8*)&A_s[ar][ac]   = cvt8(v0,v1);
      *(bf16x8*)&A_s[ar][ac+8] = cvt8(v2,v3);
    }
    { // stage B 32x32 (K-tile never straddles ksplit: both multiples of 32)
      const float* wp = (kk < ksplit)
          ? (W1 + (size_t)(jt+br)*ldw1 + kk + bc)
          : (W2 + (size_t)(jt+br)*ldw2 + (kk - ksplit) + bc);
      float4 v = *(const float4*)wp;
      bf16x4 bv;
      bv[0]=(__bf16)v.x; bv[1]=(__bf16)v.y; bv[2]=(__bf16)v.z; bv[3]=(__bf16)v.w;
      *(bf16x4*)&B_s[br][bc] = bv;
    }
    __syncthreads();
    bf16x8 a0 = *(const bf16x8*)&A_s[w*32 + la][g*8];
    bf16x8 a1 = *(const bf16x8*)&A_s[w*32 + 16 + la][g*8];
    bf16x8 b0 = *(const bf16x8*)&B_s[la][g*8];
    bf16x8 b1 = *(const bf16x8*)&B_s[16 + la][g*8];
    acc[0][0] = __builtin_amdgcn_mfma_f32_16x16x32_bf16(a0, b0, acc[0][0], 0,0,0);
    acc[0][1] = __builtin_amdgcn_mfma_f32_16x16x32_bf16(a0, b1, acc[0][1], 0,0,0);
    acc[1][0] = __builtin_amdgcn_mfma_f32_16x16x32_bf16(a1, b0, acc[1][0], 0,0,0);
    acc[1][1] = __builtin_amdgcn_mfma_f32_16x16x32_bf16(a1, b1, acc[1][1], 0,0,0);
    __syncthreads();
  }

  #pragma unroll
  for (int mfi = 0; mfi < 2; ++mfi)
    #pragma unroll
    for (int nf = 0; nf < 2; ++nf)
      #pragma unroll
      for (int r = 0; r < 4; ++r){
        int m = w*32 + mfi*16 + g*4 + r;
        int j = jt + nf*16 + la;
        float v = acc[mfi][nf][r];
        if (bias1) v += bias1[j];
        if (bias2) v += bias2[j];
        if (act == 1) v = tanh_f(v);
        C[(size_t)m*ldc + j] = v;
      }
}

// ---------------- LSTM pointwise: h1, c1 ----------------
__global__ void k_lstm(const float* __restrict__ gates, const float* __restrict__ c0,
                       float* __restrict__ out, float* __restrict__ hc)
{
  const int idx = blockIdx.x*256 + threadIdx.x;   // 0..131071
  const int b = idx >> 10, h = idx & 1023;
  const float* gp = gates + (size_t)b*4096;
  float gi = gp[h], gf = gp[1024 + h], gg = gp[2048 + h], go = gp[3072 + h];
  float c1 = sigf(gf)*c0[idx] + sigf(gi)*tanh_f(gg);
  float h1 = sigf(go)*tanh_f(c1);
  out[131072 + idx] = h1;
  out[262144 + idx] = c1;
  hc[(size_t)b*1536 + h] = h1;
}

extern "C" void kernel_launch(void* const* d_in, const int* in_sizes, int n_in,
                              void* d_out, int out_size, void* d_ws, size_t ws_size,
                              hipStream_t stream)
{
  const float* embed  = (const float*)d_in[0];
  const float* h0     = (const float*)d_in[1];
  const float* c0     = (const float*)d_in[2];
  const float* enc    = (const float*)d_in[3];
  const float* W_ph   = (const float*)d_in[4];
  const float* W_pe   = (const float*)d_in[5];
  const float* w_fc2  = (const float*)d_in[6];
  const float* W_ih   = (const float*)d_in[7];
  const float* W_hh   = (const float*)d_in[8];
  const float* b_ih   = (const float*)d_in[9];
  const float* b_hh   = (const float*)d_in[10];
  const float* W_proj = (const float*)d_in[11];
  const float* b_proj = (const float*)d_in[12];
  const unsigned char* mask = (const unsigned char*)d_in[13];

  float* ws     = (float*)d_ws;
  float* ph     = ws;                 //  32768 f32
  float* scores = ws + 32768;         //  65536 (aw in place)
  float* part   = ws + 98304;         // 262144 (4 x 128 x 512)
  float* xh     = ws + 360448;        // 262144 (128 x 2048: [embed|ctxt|h])
  float* gates  = ws + 622592;        // 524288 (128 x 4096)
  float* hc     = ws + 1146880;       // 196608 (128 x 1536: [h1|ctxt])
  float* out    = (float*)d_out;

  k_ph    <<<128, 256, 0, stream>>>(h0, W_ph, ph);
  k_concat<<<128, 256, 0, stream>>>(embed, h0, xh);
  k_scores<<<dim3(4,128), 256, 0, stream>>>(enc, W_pe, ph, w_fc2, scores);
  k_softmax<<<128, 256, 0, stream>>>(scores, mask, scores);
  k_ctxt  <<<dim3(128,4), 256, 0, stream>>>(enc, scores, part);
  k_ctxt_fin<<<128, 256, 0, stream>>>(part, xh, hc);
  k_gemm  <<<128, 256, 0, stream>>>(xh, 2048, W_ih, 1024, W_hh, 1024, 1024,
                                    b_ih, b_hh, gates, 4096, 2048, 0);
  k_lstm  <<<512, 256, 0, stream>>>(gates, c0, out, hc);
  k_gemm  <<<32, 256, 0, stream>>>(hc, 1536, W_proj, 1536, nullptr, 0, 1536,
                                   b_proj, nullptr, out, 1024, 1536, 1);
}